// Round 13
// baseline (1630.107 us; speedup 1.0000x reference)
//
#include <hip/hip_runtime.h>
#include <hip/hip_bf16.h>
#include <stdint.h>

// ============================================================================
// bayesian_nn round 12 (resubmit — R12 bench hit GPUAcquisitionTimeout):
//  - REVERT R5's C<=50 clamp (measured R11: 1313us vs R4's 1202us — loss).
//  - FUSE k_tmp + k_wh -> k_whf: Wh = (vo @ rW^T-form) @ vi^T + mu computed
//    per 128-row band with tmp held in LDS (bf16, padded), never hitting HBM.
//    R4 evidence: k_wh FETCH 269MB @ 2.3TB/s = 68% of its 173us; tmp round
//    trip (~250MB/chunk) is pure eliminable traffic.
//  - k_fwd/k_out repointed: Wh lives in bufT, h ping-pongs in bufRW.
// PRNG: JAX partitionable threefry (bit-correct since round 1).
// ============================================================================

#define NSAMP 150

typedef unsigned int u32;
typedef unsigned short ushort_t;
using short8 = __attribute__((ext_vector_type(8))) short;
using us8    = __attribute__((ext_vector_type(8))) unsigned short;
using us4    = __attribute__((ext_vector_type(4))) unsigned short;
using f32x4  = __attribute__((ext_vector_type(4))) float;

// ---------------------------------------------------------------- threefry --
__device__ __forceinline__ u32 rotl32(u32 x, int r){ return (x<<r)|(x>>(32-r)); }

__device__ __forceinline__ void tf_block(u32 k0, u32 k1, u32 x0, u32 x1, u32& o0, u32& o1){
  u32 k2 = k0 ^ k1 ^ 0x1BD11BDAu;
  x0 += k0; x1 += k1;
#define TF_R4(a,b,c,d) \
  x0+=x1; x1=rotl32(x1,a); x1^=x0; \
  x0+=x1; x1=rotl32(x1,b); x1^=x0; \
  x0+=x1; x1=rotl32(x1,c); x1^=x0; \
  x0+=x1; x1=rotl32(x1,d); x1^=x0;
  TF_R4(13,15,26,6)  x0+=k1; x1+=k2+1u;
  TF_R4(17,29,16,24) x0+=k2; x1+=k0+2u;
  TF_R4(13,15,26,6)  x0+=k0; x1+=k1+3u;
  TF_R4(17,29,16,24) x0+=k1; x1+=k2+4u;
  TF_R4(13,15,26,6)  x0+=k2; x1+=k0+5u;
#undef TF_R4
  o0=x0; o1=x1;
}

// partitionable random_bits(key,32,n)[e]: 64-bit counter (0,e), out0^out1
__device__ __forceinline__ u32 jax_bits(u32 kh, u32 kl, u32 e){
  u32 o0,o1; tf_block(kh,kl,0u,e,o0,o1); return o0^o1;
}

// ------------------------------------------------- erfinv + normal map ------
// Exact XLA structure (Giles polynomial) with libm log1pf — small kernels only.
__device__ __forceinline__ float erfinv_xla(float x){
  float w = -log1pf(-x*x);
  float p;
  if (w < 5.0f) {
    w -= 2.5f;
    p =              2.81022636e-08f;
    p = fmaf(p, w,   3.43273939e-07f);
    p = fmaf(p, w,  -3.5233877e-06f);
    p = fmaf(p, w,  -4.39150654e-06f);
    p = fmaf(p, w,   0.00021858087f);
    p = fmaf(p, w,  -0.00125372503f);
    p = fmaf(p, w,  -0.00417768164f);
    p = fmaf(p, w,   0.246640727f);
    p = fmaf(p, w,   1.50140941f);
  } else {
    w = sqrtf(w) - 3.0f;
    p =             -0.000200214257f;
    p = fmaf(p, w,   0.000100950558f);
    p = fmaf(p, w,   0.00134934322f);
    p = fmaf(p, w,  -0.00367342844f);
    p = fmaf(p, w,   0.00573950773f);
    p = fmaf(p, w,  -0.0076224613f);
    p = fmaf(p, w,   0.00943887047f);
    p = fmaf(p, w,   1.00167406f);
    p = fmaf(p, w,   2.83297682f);
  }
  return p * x;
}

// Fast variant for the bulk generator: hw log2 instead of libm log1pf.
__device__ __forceinline__ float erfinv_fast(float x){
  float y = (1.0f - x) * (1.0f + x);               // 1 - x^2, precise at |x|->1
  float w = -0.6931471805599453f * __log2f(y);     // -ln(1-x^2) via v_log_f32
  float p;
  if (w < 5.0f) {
    float t = w - 2.5f;
    p =              2.81022636e-08f;
    p = fmaf(p, t,   3.43273939e-07f);
    p = fmaf(p, t,  -3.5233877e-06f);
    p = fmaf(p, t,  -4.39150654e-06f);
    p = fmaf(p, t,   0.00021858087f);
    p = fmaf(p, t,  -0.00125372503f);
    p = fmaf(p, t,  -0.00417768164f);
    p = fmaf(p, t,   0.246640727f);
    p = fmaf(p, t,   1.50140941f);
  } else {
    float t = __fsqrt_rn(w) - 3.0f;
    p =             -0.000200214257f;
    p = fmaf(p, t,   0.000100950558f);
    p = fmaf(p, t,   0.00134934322f);
    p = fmaf(p, t,  -0.00367342844f);
    p = fmaf(p, t,   0.00573950773f);
    p = fmaf(p, t,  -0.0076224613f);
    p = fmaf(p, t,   0.00943887047f);
    p = fmaf(p, t,   1.00167406f);
    p = fmaf(p, t,   2.83297682f);
  }
  return p * x;
}

__device__ __forceinline__ float bits_to_uniform(u32 bits){
  float f = __uint_as_float((bits >> 9) | 0x3F800000u) - 1.0f;   // [0,1)
  const float lo = -0.99999994f;
  float u = fmaf(f, 2.0f, lo);
  return fmaxf(u, lo);
}

__device__ __forceinline__ float bits_to_normal(u32 bits){       // exact path
  return 1.41421356237f * erfinv_xla(bits_to_uniform(bits));
}
__device__ __forceinline__ float bits_to_normal_fast(u32 bits){  // bulk path
  return 1.41421356237f * erfinv_fast(bits_to_uniform(bits));
}

// ------------------------------------------------------------- bf16 utils --
__device__ __forceinline__ ushort_t f2bf(float x){
  u32 u = __float_as_uint(x);
  u32 r = (u + 0x7FFFu + ((u>>16)&1u)) >> 16;
  return (ushort_t)r;
}
__device__ __forceinline__ float bf2f(ushort_t u){ return __uint_as_float(((u32)u)<<16); }

__device__ __forceinline__ void gload16(const void* g, void* l){
  __builtin_amdgcn_global_load_lds((const __attribute__((address_space(1))) void*)g,
                                   (__attribute__((address_space(3))) void*)l, 16, 0, 0);
}

// ------------------------------------------------------------- key kernel --
__global__ void k_keys(u32* __restrict__ keys){
  int s = threadIdx.x;
  if (s >= NSAMP) return;
  u32 sh, sl;
  tf_block(0u,42u,0u,(u32)s,sh,sl);        // foldlike split(key(42),150)
  u32* k = keys + s*8;
  tf_block(sh,sl,0u,0u,k[0],k[1]);
  tf_block(sh,sl,0u,1u,k[2],k[3]);
  tf_block(sh,sl,0u,2u,k[4],k[5]);
  tf_block(sh,sl,0u,3u,k[6],k[7]);
}

// ----------------------------------------------- sigmaT (transpose) + cvt --
// sigT[l][b][a] = sqrt(exp(2*v_Wh[l][a][b]))
__global__ void k_sigt(const float* __restrict__ v, float* __restrict__ sT){
  __shared__ float tile[32][33];
  int lw = blockIdx.z;
  int a0 = blockIdx.y*32, b0 = blockIdx.x*32;
  const float* src = v + (size_t)lw*262144;
  #pragma unroll
  for (int i=0;i<4;++i){
    int a = a0 + threadIdx.y + i*8;
    tile[threadIdx.y + i*8][threadIdx.x] = src[(size_t)a*512 + b0 + threadIdx.x];
  }
  __syncthreads();
  float* dst = sT + (size_t)lw*262144;
  #pragma unroll
  for (int i=0;i<4;++i){
    int b = b0 + threadIdx.y + i*8;
    float vv = tile[threadIdx.x][threadIdx.y + i*8];
    dst[(size_t)b*512 + a0 + threadIdx.x] = sqrtf(expf(2.f*vv));
  }
}

__global__ __launch_bounds__(256) void k_cvt(const float* __restrict__ in,
                                             ushort_t* __restrict__ out){
  int i = (blockIdx.x*256 + threadIdx.x)*4;
  float4 v = *(const float4*)(in + i);
  us4 o; o[0]=f2bf(v.x); o[1]=f2bf(v.y); o[2]=f2bf(v.z); o[3]=f2bf(v.w);
  *(us4*)(out + i) = o;
}

// ------------------------------------------------------ rW^T generation ----
// rWT[sl][l][b][a] = normal(e(l,a,b)) * sigT[l][b][a], bf16
__global__ __launch_bounds__(256) void k_genrw(const float* __restrict__ sigT,
                                               const u32* __restrict__ keys,
                                               ushort_t* __restrict__ rWT, int s0){
  int sl = blockIdx.x / 384;
  int bi = blockIdx.x - sl*384;
  int q  = bi*256 + threadIdx.x;     // 0..98303
  int f0 = q*8;                      // flat [l][b][a]
  int lw = f0 >> 18;
  int r  = f0 & 262143;
  int b  = r >> 9;
  int a0 = r & 511;
  const u32* k = keys + (size_t)(s0+sl)*8;
  u32 kh=k[0], kl=k[1];
  u32 eb = (u32)(lw*262144 + a0*512 + b);
  float4 sa = *(const float4*)(sigT + f0);
  float4 sb = *(const float4*)(sigT + f0 + 4);
  float ss[8] = {sa.x,sa.y,sa.z,sa.w,sb.x,sb.y,sb.z,sb.w};
  us8 o;
  #pragma unroll
  for (int j=0;j<8;++j){
    float n = bits_to_normal_fast(jax_bits(kh,kl, eb + (u32)(j*512)));
    o[j] = f2bf(n * ss[j]);
  }
  *(us8*)(rWT + (size_t)sl*786432 + f0) = o;
}

// --------------------------------------------- small weights (bh, Wo, bo) ---
__global__ __launch_bounds__(512) void k_small(const float* __restrict__ mu_bh,
                                               const float* __restrict__ v_bh,
                                               const float* __restrict__ vb_bh,
                                               const float* __restrict__ mu_Wo,
                                               const float* __restrict__ v_Wo,
                                               const float* __restrict__ vo_Wo,
                                               const float* __restrict__ vi_Wo,
                                               const float* __restrict__ mu_bo,
                                               const float* __restrict__ v_bo,
                                               const float* __restrict__ vb_bo,
                                               const u32* __restrict__ keys,
                                               float* __restrict__ bh_all,
                                               float* __restrict__ Wo_all,
                                               float* __restrict__ bo_all){
  int s = blockIdx.x, t = threadIdx.x;
  const u32* k = keys + (size_t)s*8;
  __shared__ __align__(16) float rbh[1536];
  __shared__ __align__(16) float t2[1024];
  for (int e=t; e<1536; e+=512)
    rbh[e] = bits_to_normal(jax_bits(k[2],k[3],(u32)e)) * sqrtf(expf(2.f*v_bh[e]));
  {
    float r0 = bits_to_normal(jax_bits(k[4],k[5],(u32)t))       * sqrtf(expf(2.f*v_Wo[t]));
    float r1 = bits_to_normal(jax_bits(k[4],k[5],(u32)(t+512))) * sqrtf(expf(2.f*v_Wo[t+512]));
    t2[t]     = vo_Wo[0]*r0 + vo_Wo[1]*r1;
    t2[t+512] = vo_Wo[2]*r0 + vo_Wo[3]*r1;
  }
  __syncthreads();
  for (int e=t; e<1536; e+=512){
    int lw = e >> 9;
    const float* row = vb_bh + (size_t)e*512;
    const float* rb = rbh + (lw<<9);
    float acc = 0.f;
    for (int a=0;a<512;a+=4){
      float4 vv = *(const float4*)(row+a);
      acc += vv.x*rb[a] + vv.y*rb[a+1] + vv.z*rb[a+2] + vv.w*rb[a+3];
    }
    bh_all[(size_t)s*1536+e] = acc + mu_bh[e];
  }
  {
    const float* row = vi_Wo + (size_t)t*512;
    float a0=0.f, a1=0.f;
    for (int b=0;b<512;b+=4){
      float4 vv = *(const float4*)(row+b);
      a0 += vv.x*t2[b]    +vv.y*t2[b+1]    +vv.z*t2[b+2]    +vv.w*t2[b+3];
      a1 += vv.x*t2[512+b]+vv.y*t2[512+b+1]+vv.z*t2[512+b+2]+vv.w*t2[512+b+3];
    }
    Wo_all[(size_t)s*1024 + t]       = a0 + mu_Wo[t];
    Wo_all[(size_t)s*1024 + 512 + t] = a1 + mu_Wo[512+t];
  }
  if (t < 2){
    float rb0 = bits_to_normal(jax_bits(k[6],k[7],0u)) * sqrtf(expf(2.f*v_bo[0]));
    float rb1 = bits_to_normal(jax_bits(k[6],k[7],1u)) * sqrtf(expf(2.f*v_bo[1]));
    bo_all[(size_t)s*2+t] = vb_bo[t*2+0]*rb0 + vb_bo[t*2+1]*rb1 + mu_bo[t];
  }
}

// -------------------------------------- FUSED tmp+Wh kernel (new in R12) ----
// Per z (= sl*3+lw), band m0 = 128*blockIdx.x:
//   tmp[o][b] = sum_a vo[l][o][a] * rWT[z][b][a]      (phase 1, per b-slice)
//   Wh[o][i]  = sum_b tmp[o][b] * vi[l][i][b] + mu    (phase 2, acc in VGPR)
// tmp never leaves the CU: 128x128 bf16 slice in LDS (pad 8 -> 2-way banks).
// 512 threads = 8 waves as 2(m) x 4(i/b). Frag layouts = verified gemm_core.
__global__ __launch_bounds__(512) void k_whf(const ushort_t* __restrict__ vo,
                                             const ushort_t* __restrict__ vi,
                                             const float* __restrict__ mu,
                                             const ushort_t* __restrict__ rWT,
                                             ushort_t* __restrict__ Wh){
  __shared__ ushort_t A1s[4096];         // [128 o][32 k]
  __shared__ ushort_t B1s[4096];         // [128 b][32 k]
  __shared__ ushort_t Ts[128*136];       // tmp slice [128 o][128 b (+8 pad)]
  const int z = blockIdx.y, lw = z % 3;
  const ushort_t* VO = vo  + (size_t)lw*262144;
  const ushort_t* VI = vi  + (size_t)lw*262144;
  const float*    MU = mu  + (size_t)lw*262144;
  const ushort_t* RW = rWT + (size_t)z*262144;
  ushort_t*      WHO = Wh  + (size_t)z*262144;
  const int m0 = blockIdx.x * 128;
  const int t = threadIdx.x, l = t & 63, w = t >> 6;
  const int wm = w >> 2, wi = w & 3;            // wave grid 2x4
  const int srow = t >> 2, scol = (t & 3) << 3; // staging: 128 rows x 32 cols
  const int rfr = l & 15, kfr = (l >> 4) << 3;  // A/B frag indices
  const int cr = (l >> 4) << 2, cc = l & 15;    // C/D layout
  f32x4 acc2[4][8] = {};                        // [64 o][128 i] per wave
  for (int nb = 0; nb < 4; ++nb){
    const int b0 = nb * 128;
    // ---- phase 1: Ts = vo[band] @ rW[b-slice]^T (K = a = 512)
    f32x4 acc1[4][2] = {};
    for (int k0 = 0; k0 < 512; k0 += 32){
      gload16(VO + (size_t)(m0 + srow)*512 + k0 + scol, A1s + t*8);
      gload16(RW + (size_t)(b0 + srow)*512 + k0 + scol, B1s + t*8);
      __syncthreads();
      short8 af[4], bf[2];
      #pragma unroll
      for (int i=0;i<4;++i) af[i] = *(const short8*)(A1s + (wm*64 + i*16 + rfr)*32 + kfr);
      #pragma unroll
      for (int j=0;j<2;++j) bf[j] = *(const short8*)(B1s + (wi*32 + j*16 + rfr)*32 + kfr);
      #pragma unroll
      for (int i=0;i<4;++i)
        #pragma unroll
        for (int j=0;j<2;++j)
          acc1[i][j] = __builtin_amdgcn_mfma_f32_16x16x32_bf16(af[i], bf[j], acc1[i][j], 0,0,0);
      __syncthreads();
    }
    // acc1 (C-layout) -> Ts bf16
    #pragma unroll
    for (int i=0;i<4;++i)
      #pragma unroll
      for (int j=0;j<2;++j)
        #pragma unroll
        for (int r=0;r<4;++r)
          Ts[(wm*64 + i*16 + cr + r)*136 + wi*32 + j*16 + cc] = f2bf(acc1[i][j][r]);
    __syncthreads();
    // ---- phase 2 partial: acc2 += Ts[o][b] * vi[i][b0+b] (K = b = 128)
    for (int kk = 0; kk < 128; kk += 32){
      short8 a2[4];
      #pragma unroll
      for (int i=0;i<4;++i) a2[i] = *(const short8*)(Ts + (wm*64 + i*16 + rfr)*136 + kk + kfr);
      #pragma unroll
      for (int j=0;j<8;++j){
        short8 b2 = *(const short8*)(VI + (size_t)(wi*128 + j*16 + rfr)*512 + b0 + kk + kfr);
        #pragma unroll
        for (int i=0;i<4;++i)
          acc2[i][j] = __builtin_amdgcn_mfma_f32_16x16x32_bf16(a2[i], b2, acc2[i][j], 0,0,0);
      }
    }
    __syncthreads();   // protect Ts before next nb overwrites it
  }
  // ---- epilogue: Wh = acc2 + mu
  #pragma unroll
  for (int i=0;i<4;++i)
    #pragma unroll
    for (int j=0;j<8;++j)
      #pragma unroll
      for (int r=0;r<4;++r){
        int row = m0 + wm*64 + i*16 + cr + r;
        int col = wi*128 + j*16 + cc;
        WHO[(size_t)row*512 + col] = f2bf(acc2[i][j][r] + MU[(size_t)row*512 + col]);
      }
}

// ------------------------------------------- bf16 MFMA NT GEMM (m97-style) --
// C[m,n] = sum_k A[m,k]*B[n,k]; EPI 2: += E[n], relu. C stored bf16.
template<int EPI>
__device__ __forceinline__ void gemm_core(const ushort_t* __restrict__ A,
                                          const ushort_t* __restrict__ B,
                                          const float* __restrict__ E,
                                          ushort_t* __restrict__ C){
  __shared__ ushort_t As[4096];   // [128][32]
  __shared__ ushort_t Bs[4096];
  const int t = threadIdx.x;
  const int l = t & 63;
  const int m0 = blockIdx.y * 128, n0 = blockIdx.x * 128;
  const int wr = (t >> 7) & 1, wc = (t >> 6) & 1;
  const int srow = t >> 2, scol = (t & 3) << 3;
  const ushort_t* Ag = A + (size_t)(m0 + srow) * 512 + scol;
  const ushort_t* Bg = B + (size_t)(n0 + srow) * 512 + scol;
  ushort_t* Al = As + t * 8;
  ushort_t* Bl = Bs + t * 8;
  const int rfr = l & 15, kfr = (l >> 4) << 3;
  f32x4 acc[4][4] = {};
  for (int k0 = 0; k0 < 512; k0 += 32) {
    gload16(Ag + k0, Al);
    gload16(Ag + 64*512 + k0, Al + 2048);
    gload16(Bg + k0, Bl);
    gload16(Bg + 64*512 + k0, Bl + 2048);
    __syncthreads();
    short8 af[4], bfv[4];
    #pragma unroll
    for (int i=0;i<4;++i){
      af[i]  = *(const short8*)(As + (wr*64 + i*16 + rfr)*32 + kfr);
      bfv[i] = *(const short8*)(Bs + (wc*64 + i*16 + rfr)*32 + kfr);
    }
    #pragma unroll
    for (int i=0;i<4;++i)
      #pragma unroll
      for (int j=0;j<4;++j)
        acc[i][j] = __builtin_amdgcn_mfma_f32_16x16x32_bf16(af[i], bfv[j], acc[i][j], 0, 0, 0);
    __syncthreads();
  }
  const int cr = (l >> 4) << 2, cc = l & 15;
  #pragma unroll
  for (int i=0;i<4;++i){
    #pragma unroll
    for (int j=0;j<4;++j){
      int row = m0 + wr*64 + i*16 + cr;
      int col = n0 + wc*64 + j*16 + cc;
      #pragma unroll
      for (int r=0;r<4;++r){
        float v = acc[i][j][r];
        if (EPI==2) v = fmaxf(v + E[col], 0.f);
        C[(size_t)(row+r)*512 + col] = f2bf(v);
      }
    }
  }
}

// h' = relu(h @ Wh^T + bh) ; Wh lives in bufT, h ping-pongs in bufRW
__global__ __launch_bounds__(256) void k_fwd(const ushort_t* __restrict__ xbf,
                                             const ushort_t* __restrict__ Wh,
                                             const float* __restrict__ bh_all,
                                             ushort_t* __restrict__ hb, int lw, int s0){
  int sl = blockIdx.z;
  ushort_t* hbase = hb + (size_t)sl*786432;
  const ushort_t* A = (lw==0) ? xbf : (hbase + (lw==2 ? 262144 : 0));
  ushort_t* O = hbase + (lw==1 ? 262144 : 0);
  gemm_core<2>(A, Wh + (size_t)(sl*3+lw)*262144,
               bh_all + (size_t)(s0+sl)*1536 + (size_t)lw*512, O);
}

// out[s][b][c] = h[b,:] . Wo[s][c,:] + bo[s][c]
__global__ __launch_bounds__(256) void k_out(const ushort_t* __restrict__ hb,
                                             const float* __restrict__ Wo_all,
                                             const float* __restrict__ bo_all,
                                             float* __restrict__ out, int s0){
  int sl = blockIdx.x;
  int b = blockIdx.y*256 + threadIdx.x;
  const ushort_t* h = hb + (size_t)sl*786432 + (size_t)b*512;
  int s = s0 + sl;
  const float* W0 = Wo_all + (size_t)s*1024;
  const float* W1 = W0 + 512;
  float a0=0.f, a1=0.f;
  for (int i=0;i<512;i+=8){
    us8 hv = *(const us8*)(h+i);
    #pragma unroll
    for (int j=0;j<8;++j){
      float hf = bf2f(hv[j]);
      a0 = fmaf(hf, W0[i+j], a0);
      a1 = fmaf(hf, W1[i+j], a1);
    }
  }
  out[((size_t)s*512 + b)*2 + 0] = a0 + bo_all[(size_t)s*2+0];
  out[((size_t)s*512 + b)*2 + 1] = a1 + bo_all[(size_t)s*2+1];
}

// ---------------------------------------------------------------- launch ----
extern "C" void kernel_launch(void* const* d_in, const int* in_sizes, int n_in,
                              void* d_out, int out_size, void* d_ws, size_t ws_size,
                              hipStream_t stream){
  const float* x      = (const float*)d_in[0];
  const float* mu_Wh  = (const float*)d_in[1];
  const float* v_Wh   = (const float*)d_in[2];
  const float* vo_Wh  = (const float*)d_in[3];
  const float* vi_Wh  = (const float*)d_in[4];
  const float* mu_bh  = (const float*)d_in[5];
  const float* v_bh   = (const float*)d_in[6];
  const float* vb_bh  = (const float*)d_in[7];
  const float* mu_Wo  = (const float*)d_in[8];
  const float* v_Wo   = (const float*)d_in[9];
  const float* vo_Wo  = (const float*)d_in[10];
  const float* vi_Wo  = (const float*)d_in[11];
  const float* mu_bo  = (const float*)d_in[12];
  const float* v_bo   = (const float*)d_in[13];
  const float* vb_bo  = (const float*)d_in[14];
  float* out = (float*)d_out;

  char* ws = (char*)d_ws;
  // fixed region (8 MB): keys | bh_all | Wo_all | bo_all | sigT | vo_bf | vi_bf | xbf
  u32*      keys   = (u32*)(ws + 0);            // 4800 B
  float*    bh_all = (float*)(ws + 8192);       // 921600 B
  float*    Wo_all = (float*)(ws + 929792);     // 614400 B
  float*    bo_all = (float*)(ws + 1544192);    // 1200 B
  float*    sigT   = (float*)(ws + 1546240);    // 3 MB
  ushort_t* vo_bf  = (ushort_t*)(ws + 4691968); // 1.5 MB
  ushort_t* vi_bf  = (ushort_t*)(ws + 6264832); // 1.5 MB
  ushort_t* xbf    = (ushort_t*)(ws + 7837696); // 0.5 MB
  const size_t big_off = 8388608;
  const size_t per_sample_b = 2u * 1572864u;    // rWT buf + Wh/h buf (bf16)
  size_t avail = (ws_size > big_off) ? (ws_size - big_off) : 0;
  int C = (int)(avail / per_sample_b);          // R12: clamp reverted (R11: -9%)
  if (C < 1) C = 1;
  if (C > NSAMP) C = NSAMP;
  ushort_t* bufRW = (ushort_t*)(ws + big_off);        // [C][3][512][512] rWT -> h ping-pong
  ushort_t* bufT  = bufRW + (size_t)C*786432;         // [C][3][512][512] Wh

  hipLaunchKernelGGL(k_keys, dim3(1), dim3(256), 0, stream, keys);
  hipLaunchKernelGGL(k_small, dim3(NSAMP), dim3(512), 0, stream,
                     mu_bh, v_bh, vb_bh, mu_Wo, v_Wo, vo_Wo, vi_Wo,
                     mu_bo, v_bo, vb_bo, keys, bh_all, Wo_all, bo_all);
  hipLaunchKernelGGL(k_sigt, dim3(16,16,3), dim3(32,8), 0, stream, v_Wh, sigT);
  hipLaunchKernelGGL(k_cvt, dim3(768), dim3(256), 0, stream, vo_Wh, vo_bf);
  hipLaunchKernelGGL(k_cvt, dim3(768), dim3(256), 0, stream, vi_Wh, vi_bf);
  hipLaunchKernelGGL(k_cvt, dim3(256), dim3(256), 0, stream, x, xbf);

  for (int s0 = 0; s0 < NSAMP; s0 += C){
    int Cc = (NSAMP - s0 < C) ? (NSAMP - s0) : C;
    hipLaunchKernelGGL(k_genrw, dim3(Cc*384), dim3(256), 0, stream, sigT, keys, bufRW, s0);
    hipLaunchKernelGGL(k_whf, dim3(4, Cc*3), dim3(512), 0, stream,
                       vo_bf, vi_bf, mu_Wh, bufRW, bufT);
    for (int lw = 0; lw < 3; ++lw)
      hipLaunchKernelGGL(k_fwd, dim3(4,4,Cc), dim3(256), 0, stream, xbf, bufT, bh_all, bufRW, lw, s0);
    hipLaunchKernelGGL(k_out, dim3(Cc,2), dim3(256), 0, stream, bufRW, Wo_all, bo_all, out, s0);
  }
  (void)in_sizes; (void)n_in; (void)out_size;
}

// Round 14
// 1185.310 us; speedup vs baseline: 1.3753x; 1.3753x over previous
//
#include <hip/hip_runtime.h>
#include <hip/hip_bf16.h>
#include <stdint.h>

// ============================================================================
// bayesian_nn round 14: REVERT R13 fusion (466us x2 vs 345us x2 split; FETCH
// went UP 512MB from cross-XCD redundant rWT reads). Back to verified R4
// structure (1202us) + ONE change: bijective chunked XCD swizzle (T1) on the
// three GEMM kernels. R13's own counters showed panel re-reads across blocks
// on different XCDs are the HBM-traffic driver (k_wh: tmp panel read 4x, 504MB
// logical, 269MB after L3). Chunked swizzle puts the 16 blocks of one z on one
// XCD so shared panels hit L2.
// PRNG: JAX partitionable threefry (bit-correct since round 1).
// ============================================================================

#define NSAMP 150

typedef unsigned int u32;
typedef unsigned short ushort_t;
using short8 = __attribute__((ext_vector_type(8))) short;
using us8    = __attribute__((ext_vector_type(8))) unsigned short;
using us4    = __attribute__((ext_vector_type(4))) unsigned short;
using f32x4  = __attribute__((ext_vector_type(4))) float;

// ---------------------------------------------------------------- threefry --
__device__ __forceinline__ u32 rotl32(u32 x, int r){ return (x<<r)|(x>>(32-r)); }

__device__ __forceinline__ void tf_block(u32 k0, u32 k1, u32 x0, u32 x1, u32& o0, u32& o1){
  u32 k2 = k0 ^ k1 ^ 0x1BD11BDAu;
  x0 += k0; x1 += k1;
#define TF_R4(a,b,c,d) \
  x0+=x1; x1=rotl32(x1,a); x1^=x0; \
  x0+=x1; x1=rotl32(x1,b); x1^=x0; \
  x0+=x1; x1=rotl32(x1,c); x1^=x0; \
  x0+=x1; x1=rotl32(x1,d); x1^=x0;
  TF_R4(13,15,26,6)  x0+=k1; x1+=k2+1u;
  TF_R4(17,29,16,24) x0+=k2; x1+=k0+2u;
  TF_R4(13,15,26,6)  x0+=k0; x1+=k1+3u;
  TF_R4(17,29,16,24) x0+=k1; x1+=k2+4u;
  TF_R4(13,15,26,6)  x0+=k2; x1+=k0+5u;
#undef TF_R4
  o0=x0; o1=x1;
}

// partitionable random_bits(key,32,n)[e]: 64-bit counter (0,e), out0^out1
__device__ __forceinline__ u32 jax_bits(u32 kh, u32 kl, u32 e){
  u32 o0,o1; tf_block(kh,kl,0u,e,o0,o1); return o0^o1;
}

// ------------------------------------------------- erfinv + normal map ------
// Exact XLA structure (Giles polynomial) with libm log1pf — small kernels only.
__device__ __forceinline__ float erfinv_xla(float x){
  float w = -log1pf(-x*x);
  float p;
  if (w < 5.0f) {
    w -= 2.5f;
    p =              2.81022636e-08f;
    p = fmaf(p, w,   3.43273939e-07f);
    p = fmaf(p, w,  -3.5233877e-06f);
    p = fmaf(p, w,  -4.39150654e-06f);
    p = fmaf(p, w,   0.00021858087f);
    p = fmaf(p, w,  -0.00125372503f);
    p = fmaf(p, w,  -0.00417768164f);
    p = fmaf(p, w,   0.246640727f);
    p = fmaf(p, w,   1.50140941f);
  } else {
    w = sqrtf(w) - 3.0f;
    p =             -0.000200214257f;
    p = fmaf(p, w,   0.000100950558f);
    p = fmaf(p, w,   0.00134934322f);
    p = fmaf(p, w,  -0.00367342844f);
    p = fmaf(p, w,   0.00573950773f);
    p = fmaf(p, w,  -0.0076224613f);
    p = fmaf(p, w,   0.00943887047f);
    p = fmaf(p, w,   1.00167406f);
    p = fmaf(p, w,   2.83297682f);
  }
  return p * x;
}

// Fast variant for the bulk generator: hw log2 instead of libm log1pf.
__device__ __forceinline__ float erfinv_fast(float x){
  float y = (1.0f - x) * (1.0f + x);               // 1 - x^2, precise at |x|->1
  float w = -0.6931471805599453f * __log2f(y);     // -ln(1-x^2) via v_log_f32
  float p;
  if (w < 5.0f) {
    float t = w - 2.5f;
    p =              2.81022636e-08f;
    p = fmaf(p, t,   3.43273939e-07f);
    p = fmaf(p, t,  -3.5233877e-06f);
    p = fmaf(p, t,  -4.39150654e-06f);
    p = fmaf(p, t,   0.00021858087f);
    p = fmaf(p, t,  -0.00125372503f);
    p = fmaf(p, t,  -0.00417768164f);
    p = fmaf(p, t,   0.246640727f);
    p = fmaf(p, t,   1.50140941f);
  } else {
    float t = __fsqrt_rn(w) - 3.0f;
    p =             -0.000200214257f;
    p = fmaf(p, t,   0.000100950558f);
    p = fmaf(p, t,   0.00134934322f);
    p = fmaf(p, t,  -0.00367342844f);
    p = fmaf(p, t,   0.00573950773f);
    p = fmaf(p, t,  -0.0076224613f);
    p = fmaf(p, t,   0.00943887047f);
    p = fmaf(p, t,   1.00167406f);
    p = fmaf(p, t,   2.83297682f);
  }
  return p * x;
}

__device__ __forceinline__ float bits_to_uniform(u32 bits){
  float f = __uint_as_float((bits >> 9) | 0x3F800000u) - 1.0f;   // [0,1)
  const float lo = -0.99999994f;
  float u = fmaf(f, 2.0f, lo);
  return fmaxf(u, lo);
}

__device__ __forceinline__ float bits_to_normal(u32 bits){       // exact path
  return 1.41421356237f * erfinv_xla(bits_to_uniform(bits));
}
__device__ __forceinline__ float bits_to_normal_fast(u32 bits){  // bulk path
  return 1.41421356237f * erfinv_fast(bits_to_uniform(bits));
}

// ------------------------------------------------------------- bf16 utils --
__device__ __forceinline__ ushort_t f2bf(float x){
  u32 u = __float_as_uint(x);
  u32 r = (u + 0x7FFFu + ((u>>16)&1u)) >> 16;
  return (ushort_t)r;
}
__device__ __forceinline__ float bf2f(ushort_t u){ return __uint_as_float(((u32)u)<<16); }

__device__ __forceinline__ void gload16(const void* g, void* l){
  __builtin_amdgcn_global_load_lds((const __attribute__((address_space(1))) void*)g,
                                   (__attribute__((address_space(3))) void*)l, 16, 0, 0);
}

// -------------------------------------------------- XCD chunked swizzle -----
// 1D grid, nwg always = 16*k (divisible by 8). HW round-robins blocks over 8
// XCDs; remap so each XCD gets a CONTIGUOUS range of logical block ids ->
// the 16 blocks of one z (sharing A/B panels) land on one XCD's L2.
__device__ __forceinline__ void xcd_decomp(int& z, int& m0, int& n0){
  int nwg = gridDim.x;
  int f   = blockIdx.x;
  int swz = (f & 7) * (nwg >> 3) + (f >> 3);
  z  = swz >> 4;
  int r = swz & 15;
  m0 = (r >> 2) << 7;
  n0 = (r & 3) << 7;
}

// ------------------------------------------------------------- key kernel --
__global__ void k_keys(u32* __restrict__ keys){
  int s = threadIdx.x;
  if (s >= NSAMP) return;
  u32 sh, sl;
  tf_block(0u,42u,0u,(u32)s,sh,sl);        // foldlike split(key(42),150)
  u32* k = keys + s*8;
  tf_block(sh,sl,0u,0u,k[0],k[1]);
  tf_block(sh,sl,0u,1u,k[2],k[3]);
  tf_block(sh,sl,0u,2u,k[4],k[5]);
  tf_block(sh,sl,0u,3u,k[6],k[7]);
}

// ----------------------------------------------- sigmaT (transpose) + cvt --
// sigT[l][b][a] = sqrt(exp(2*v_Wh[l][a][b]))
__global__ void k_sigt(const float* __restrict__ v, float* __restrict__ sT){
  __shared__ float tile[32][33];
  int lw = blockIdx.z;
  int a0 = blockIdx.y*32, b0 = blockIdx.x*32;
  const float* src = v + (size_t)lw*262144;
  #pragma unroll
  for (int i=0;i<4;++i){
    int a = a0 + threadIdx.y + i*8;
    tile[threadIdx.y + i*8][threadIdx.x] = src[(size_t)a*512 + b0 + threadIdx.x];
  }
  __syncthreads();
  float* dst = sT + (size_t)lw*262144;
  #pragma unroll
  for (int i=0;i<4;++i){
    int b = b0 + threadIdx.y + i*8;
    float vv = tile[threadIdx.x][threadIdx.y + i*8];
    dst[(size_t)b*512 + a0 + threadIdx.x] = sqrtf(expf(2.f*vv));
  }
}

__global__ __launch_bounds__(256) void k_cvt(const float* __restrict__ in,
                                             ushort_t* __restrict__ out){
  int i = (blockIdx.x*256 + threadIdx.x)*4;
  float4 v = *(const float4*)(in + i);
  us4 o; o[0]=f2bf(v.x); o[1]=f2bf(v.y); o[2]=f2bf(v.z); o[3]=f2bf(v.w);
  *(us4*)(out + i) = o;
}

// ------------------------------------------------------ rW^T generation ----
// rWT[sl][l][b][a] = normal(e(l,a,b)) * sigT[l][b][a], bf16
__global__ __launch_bounds__(256) void k_genrw(const float* __restrict__ sigT,
                                               const u32* __restrict__ keys,
                                               ushort_t* __restrict__ rWT, int s0){
  int sl = blockIdx.x / 384;
  int bi = blockIdx.x - sl*384;
  int q  = bi*256 + threadIdx.x;     // 0..98303
  int f0 = q*8;                      // flat [l][b][a]
  int lw = f0 >> 18;
  int r  = f0 & 262143;
  int b  = r >> 9;
  int a0 = r & 511;
  const u32* k = keys + (size_t)(s0+sl)*8;
  u32 kh=k[0], kl=k[1];
  u32 eb = (u32)(lw*262144 + a0*512 + b);
  float4 sa = *(const float4*)(sigT + f0);
  float4 sb = *(const float4*)(sigT + f0 + 4);
  float ss[8] = {sa.x,sa.y,sa.z,sa.w,sb.x,sb.y,sb.z,sb.w};
  us8 o;
  #pragma unroll
  for (int j=0;j<8;++j){
    float n = bits_to_normal_fast(jax_bits(kh,kl, eb + (u32)(j*512)));
    o[j] = f2bf(n * ss[j]);
  }
  *(us8*)(rWT + (size_t)sl*786432 + f0) = o;
}

// --------------------------------------------- small weights (bh, Wo, bo) ---
__global__ __launch_bounds__(512) void k_small(const float* __restrict__ mu_bh,
                                               const float* __restrict__ v_bh,
                                               const float* __restrict__ vb_bh,
                                               const float* __restrict__ mu_Wo,
                                               const float* __restrict__ v_Wo,
                                               const float* __restrict__ vo_Wo,
                                               const float* __restrict__ vi_Wo,
                                               const float* __restrict__ mu_bo,
                                               const float* __restrict__ v_bo,
                                               const float* __restrict__ vb_bo,
                                               const u32* __restrict__ keys,
                                               float* __restrict__ bh_all,
                                               float* __restrict__ Wo_all,
                                               float* __restrict__ bo_all){
  int s = blockIdx.x, t = threadIdx.x;
  const u32* k = keys + (size_t)s*8;
  __shared__ __align__(16) float rbh[1536];
  __shared__ __align__(16) float t2[1024];
  for (int e=t; e<1536; e+=512)
    rbh[e] = bits_to_normal(jax_bits(k[2],k[3],(u32)e)) * sqrtf(expf(2.f*v_bh[e]));
  {
    float r0 = bits_to_normal(jax_bits(k[4],k[5],(u32)t))       * sqrtf(expf(2.f*v_Wo[t]));
    float r1 = bits_to_normal(jax_bits(k[4],k[5],(u32)(t+512))) * sqrtf(expf(2.f*v_Wo[t+512]));
    t2[t]     = vo_Wo[0]*r0 + vo_Wo[1]*r1;
    t2[t+512] = vo_Wo[2]*r0 + vo_Wo[3]*r1;
  }
  __syncthreads();
  for (int e=t; e<1536; e+=512){
    int lw = e >> 9;
    const float* row = vb_bh + (size_t)e*512;
    const float* rb = rbh + (lw<<9);
    float acc = 0.f;
    for (int a=0;a<512;a+=4){
      float4 vv = *(const float4*)(row+a);
      acc += vv.x*rb[a] + vv.y*rb[a+1] + vv.z*rb[a+2] + vv.w*rb[a+3];
    }
    bh_all[(size_t)s*1536+e] = acc + mu_bh[e];
  }
  {
    const float* row = vi_Wo + (size_t)t*512;
    float a0=0.f, a1=0.f;
    for (int b=0;b<512;b+=4){
      float4 vv = *(const float4*)(row+b);
      a0 += vv.x*t2[b]    +vv.y*t2[b+1]    +vv.z*t2[b+2]    +vv.w*t2[b+3];
      a1 += vv.x*t2[512+b]+vv.y*t2[512+b+1]+vv.z*t2[512+b+2]+vv.w*t2[512+b+3];
    }
    Wo_all[(size_t)s*1024 + t]       = a0 + mu_Wo[t];
    Wo_all[(size_t)s*1024 + 512 + t] = a1 + mu_Wo[512+t];
  }
  if (t < 2){
    float rb0 = bits_to_normal(jax_bits(k[6],k[7],0u)) * sqrtf(expf(2.f*v_bo[0]));
    float rb1 = bits_to_normal(jax_bits(k[6],k[7],1u)) * sqrtf(expf(2.f*v_bo[1]));
    bo_all[(size_t)s*2+t] = vb_bo[t*2+0]*rb0 + vb_bo[t*2+1]*rb1 + mu_bo[t];
  }
}

// ------------------------------------------- bf16 MFMA NT GEMM (m97-style) --
// C[m,n] = sum_k A[m,k]*B[n,k], A/B bf16 row-major LDA=LDB=512, acc f32.
// EPI: 0 none; 1 += E[m*512+n] (f32); 2 += E[n], relu.  C stored bf16.
// m0/n0 passed in (R14: computed via XCD swizzle by callers).
template<int EPI>
__device__ __forceinline__ void gemm_core(const ushort_t* __restrict__ A,
                                          const ushort_t* __restrict__ B,
                                          const float* __restrict__ E,
                                          ushort_t* __restrict__ C,
                                          int m0, int n0){
  __shared__ ushort_t As[4096];   // [128][32]
  __shared__ ushort_t Bs[4096];
  const int t = threadIdx.x;
  const int l = t & 63;
  const int wr = (t >> 7) & 1, wc = (t >> 6) & 1;
  const int srow = t >> 2, scol = (t & 3) << 3;
  const ushort_t* Ag = A + (size_t)(m0 + srow) * 512 + scol;
  const ushort_t* Bg = B + (size_t)(n0 + srow) * 512 + scol;
  ushort_t* Al = As + t * 8;
  ushort_t* Bl = Bs + t * 8;
  const int rfr = l & 15, kfr = (l >> 4) << 3;
  f32x4 acc[4][4] = {};
  for (int k0 = 0; k0 < 512; k0 += 32) {
    gload16(Ag + k0, Al);
    gload16(Ag + 64*512 + k0, Al + 2048);
    gload16(Bg + k0, Bl);
    gload16(Bg + 64*512 + k0, Bl + 2048);
    __syncthreads();
    short8 af[4], bfv[4];
    #pragma unroll
    for (int i=0;i<4;++i){
      af[i]  = *(const short8*)(As + (wr*64 + i*16 + rfr)*32 + kfr);
      bfv[i] = *(const short8*)(Bs + (wc*64 + i*16 + rfr)*32 + kfr);
    }
    #pragma unroll
    for (int i=0;i<4;++i)
      #pragma unroll
      for (int j=0;j<4;++j)
        acc[i][j] = __builtin_amdgcn_mfma_f32_16x16x32_bf16(af[i], bfv[j], acc[i][j], 0, 0, 0);
    __syncthreads();
  }
  const int cr = (l >> 4) << 2, cc = l & 15;
  float4 bias;
  if (EPI==2) bias = *(const float4*)(E + n0 + 0);   // placeholder, per-col below
  #pragma unroll
  for (int i=0;i<4;++i){
    #pragma unroll
    for (int j=0;j<4;++j){
      int row = m0 + wr*64 + i*16 + cr;
      int col = n0 + wc*64 + j*16 + cc;
      #pragma unroll
      for (int r=0;r<4;++r){
        float v = acc[i][j][r];
        if (EPI==1) v += E[(size_t)(row+r)*512 + col];
        if (EPI==2) v = fmaxf(v + E[col], 0.f);
        C[(size_t)(row+r)*512 + col] = f2bf(v);
      }
    }
  }
  (void)bias;
}

// tmp[o][b] = sum_a vo[l][o][a] * rWT[z][b][a]     (1D grid, XCD-swizzled)
__global__ __launch_bounds__(256) void k_tmp(const ushort_t* __restrict__ vo,
                                             const ushort_t* __restrict__ rWT,
                                             ushort_t* __restrict__ tmp){
  int z, m0, n0; xcd_decomp(z, m0, n0);
  int lw = z % 3;
  gemm_core<0>(vo + (size_t)lw*262144, rWT + (size_t)z*262144, nullptr,
               tmp + (size_t)z*262144, m0, n0);
}

// Wh[o][i] = sum_b tmp[z][o][b] * vi[l][i][b] + mu[l][o][i]
__global__ __launch_bounds__(256) void k_wh(const ushort_t* __restrict__ tmp,
                                            const ushort_t* __restrict__ vi,
                                            const float* __restrict__ mu,
                                            ushort_t* __restrict__ Wh){
  int z, m0, n0; xcd_decomp(z, m0, n0);
  int lw = z % 3;
  gemm_core<1>(tmp + (size_t)z*262144, vi + (size_t)lw*262144,
               mu + (size_t)lw*262144, Wh + (size_t)z*262144, m0, n0);
}

// h' = relu(h @ Wh^T + bh)   (z = sample slot)
__global__ __launch_bounds__(256) void k_fwd(const ushort_t* __restrict__ xbf,
                                             const ushort_t* __restrict__ Wh,
                                             const float* __restrict__ bh_all,
                                             ushort_t* __restrict__ hb, int lw, int s0){
  int sl, m0, n0; xcd_decomp(sl, m0, n0);
  ushort_t* hbase = hb + (size_t)sl*786432;
  const ushort_t* A = (lw==0) ? xbf : (hbase + (lw==2 ? 262144 : 0));
  ushort_t* O = hbase + (lw==1 ? 262144 : 0);
  gemm_core<2>(A, Wh + (size_t)(sl*3+lw)*262144,
               bh_all + (size_t)(s0+sl)*1536 + (size_t)lw*512, O, m0, n0);
}

// out[s][b][c] = h[b,:] . Wo[s][c,:] + bo[s][c]
__global__ __launch_bounds__(256) void k_out(const ushort_t* __restrict__ hb,
                                             const float* __restrict__ Wo_all,
                                             const float* __restrict__ bo_all,
                                             float* __restrict__ out, int s0){
  int sl = blockIdx.x;
  int b = blockIdx.y*256 + threadIdx.x;
  const ushort_t* h = hb + (size_t)sl*786432 + (size_t)b*512;
  int s = s0 + sl;
  const float* W0 = Wo_all + (size_t)s*1024;
  const float* W1 = W0 + 512;
  float a0=0.f, a1=0.f;
  for (int i=0;i<512;i+=8){
    us8 hv = *(const us8*)(h+i);
    #pragma unroll
    for (int j=0;j<8;++j){
      float hf = bf2f(hv[j]);
      a0 = fmaf(hf, W0[i+j], a0);
      a1 = fmaf(hf, W1[i+j], a1);
    }
  }
  out[((size_t)s*512 + b)*2 + 0] = a0 + bo_all[(size_t)s*2+0];
  out[((size_t)s*512 + b)*2 + 1] = a1 + bo_all[(size_t)s*2+1];
}

// ---------------------------------------------------------------- launch ----
extern "C" void kernel_launch(void* const* d_in, const int* in_sizes, int n_in,
                              void* d_out, int out_size, void* d_ws, size_t ws_size,
                              hipStream_t stream){
  const float* x      = (const float*)d_in[0];
  const float* mu_Wh  = (const float*)d_in[1];
  const float* v_Wh   = (const float*)d_in[2];
  const float* vo_Wh  = (const float*)d_in[3];
  const float* vi_Wh  = (const float*)d_in[4];
  const float* mu_bh  = (const float*)d_in[5];
  const float* v_bh   = (const float*)d_in[6];
  const float* vb_bh  = (const float*)d_in[7];
  const float* mu_Wo  = (const float*)d_in[8];
  const float* v_Wo   = (const float*)d_in[9];
  const float* vo_Wo  = (const float*)d_in[10];
  const float* vi_Wo  = (const float*)d_in[11];
  const float* mu_bo  = (const float*)d_in[12];
  const float* v_bo   = (const float*)d_in[13];
  const float* vb_bo  = (const float*)d_in[14];
  float* out = (float*)d_out;

  char* ws = (char*)d_ws;
  // fixed region (8 MB): keys | bh_all | Wo_all | bo_all | sigT | vo_bf | vi_bf | xbf
  u32*      keys   = (u32*)(ws + 0);            // 4800 B
  float*    bh_all = (float*)(ws + 8192);       // 921600 B
  float*    Wo_all = (float*)(ws + 929792);     // 614400 B
  float*    bo_all = (float*)(ws + 1544192);    // 1200 B
  float*    sigT   = (float*)(ws + 1546240);    // 3 MB
  ushort_t* vo_bf  = (ushort_t*)(ws + 4691968); // 1.5 MB
  ushort_t* vi_bf  = (ushort_t*)(ws + 6264832); // 1.5 MB
  ushort_t* xbf    = (ushort_t*)(ws + 7837696); // 0.5 MB
  const size_t big_off = 8388608;
  const size_t per_sample_b = 2u * 1572864u;    // rWT/Wh buf + tmp/h buf (bf16)
  size_t avail = (ws_size > big_off) ? (ws_size - big_off) : 0;
  int C = (int)(avail / per_sample_b);          // no clamp (R11: clamp = -9%)
  if (C < 1) C = 1;
  if (C > NSAMP) C = NSAMP;
  ushort_t* bufRW = (ushort_t*)(ws + big_off);        // [C][3][512][512] rWT -> Wh
  ushort_t* bufT  = bufRW + (size_t)C*786432;         // [C][3][512][512] tmp -> h ping-pong

  hipLaunchKernelGGL(k_keys, dim3(1), dim3(256), 0, stream, keys);
  hipLaunchKernelGGL(k_small, dim3(NSAMP), dim3(512), 0, stream,
                     mu_bh, v_bh, vb_bh, mu_Wo, v_Wo, vo_Wo, vi_Wo,
                     mu_bo, v_bo, vb_bo, keys, bh_all, Wo_all, bo_all);
  hipLaunchKernelGGL(k_sigt, dim3(16,16,3), dim3(32,8), 0, stream, v_Wh, sigT);
  hipLaunchKernelGGL(k_cvt, dim3(768), dim3(256), 0, stream, vo_Wh, vo_bf);
  hipLaunchKernelGGL(k_cvt, dim3(768), dim3(256), 0, stream, vi_Wh, vi_bf);
  hipLaunchKernelGGL(k_cvt, dim3(256), dim3(256), 0, stream, x, xbf);

  for (int s0 = 0; s0 < NSAMP; s0 += C){
    int Cc = (NSAMP - s0 < C) ? (NSAMP - s0) : C;
    hipLaunchKernelGGL(k_genrw, dim3(Cc*384), dim3(256), 0, stream, sigT, keys, bufRW, s0);
    hipLaunchKernelGGL(k_tmp, dim3(16*Cc*3), dim3(256), 0, stream, vo_bf, bufRW, bufT);
    hipLaunchKernelGGL(k_wh,  dim3(16*Cc*3), dim3(256), 0, stream, bufT, vi_bf, mu_Wh, bufRW);
    for (int lw = 0; lw < 3; ++lw)
      hipLaunchKernelGGL(k_fwd, dim3(16*Cc), dim3(256), 0, stream, xbf, bufRW, bh_all, bufT, lw, s0);
    hipLaunchKernelGGL(k_out, dim3(Cc,2), dim3(256), 0, stream, bufT, Wo_all, bo_all, out, s0);
  }
  (void)in_sizes; (void)n_in; (void)out_size;
}